// Round 1
// baseline (254.861 us; speedup 1.0000x reference)
//
#include <hip/hip_runtime.h>

namespace {

constexpr int Tn = 1000;   // time steps
constexpr int Fn = 22;     // input features
constexpr int Hn = 10;     // hidden
constexpr int Cn = 4;      // classes

constexpr int CHUNK = 16;               // time steps staged per LDS chunk
constexpr int F2S   = Fn / 2;           // 11 float2 per step
constexpr int F2B   = CHUNK * F2S;      // 176 float2 per batch per chunk
constexpr int F2BP  = F2B + 1;          // padded stride: 177 (bank de-conflict)
constexpr int BUF   = 4 * F2BP;         // 708 float2 per buffer (4 batches)
constexpr int ROWF2 = Tn * F2S;         // 11000 float2 per batch row of x
constexpr int NFULL = Tn / CHUNK;       // 62 full chunks
constexpr int TAIL  = Tn - NFULL * CHUNK; // 8 remaining steps

__global__ __launch_bounds__(64, 1) void rnn_fused(
    const float* __restrict__ x,
    const float* __restrict__ w_ih0, const float* __restrict__ w_hh0,
    const float* __restrict__ b_ih0, const float* __restrict__ b_hh0,
    const float* __restrict__ w_ih1, const float* __restrict__ w_hh1,
    const float* __restrict__ b_ih1, const float* __restrict__ b_hh1,
    const float* __restrict__ w_lin, const float* __restrict__ b_lin,
    float* __restrict__ out)
{
    // double-buffered x staging: [2][4 batches][177 float2]
    __shared__ float2 lbuf[2 * BUF];   // 11328 B

    const int lane = threadIdx.x;          // 0..63 (one wave per block)
    const int g    = lane >> 4;            // group within wave: 0..3
    const int j    = lane & 15;            // lane within group (neuron id)
    const int b    = blockIdx.x * 4 + g;   // batch element
    const int jr   = (j < Hn) ? j : 0;     // clamped row for weight loads
    const int jc   = (j < Cn) ? j : 0;
    const int permbase = (lane & 48) << 2; // byte base of group's lane 0

    // ---- per-neuron weights into registers ----
    float wih0[Fn], whh0[Hn], wih1[Hn], whh1[Hn], wlin[Hn];
    #pragma unroll
    for (int f = 0; f < Fn; ++f) wih0[f] = w_ih0[jr * Fn + f];
    #pragma unroll
    for (int k = 0; k < Hn; ++k) {
        whh0[k] = w_hh0[jr * Hn + k];
        wih1[k] = w_ih1[jr * Hn + k];
        whh1[k] = w_hh1[jr * Hn + k];
        wlin[k] = w_lin[jc * Hn + k];
    }
    const float bias1 = b_ih0[jr] + b_hh0[jr];
    const float bias2 = b_ih1[jr] + b_hh1[jr];
    const float blin  = b_lin[jc];

    // ---- staging geometry (fixed per thread): flat float2 q = lane + 64*i ----
    int srcoff[F2S], maxoff[F2S], dstoff[F2S];
    #pragma unroll
    for (int i = 0; i < F2S; ++i) {
        const int q  = lane + 64 * i;      // 0..703
        const int gq = q / F2B;            // which batch row (0..3)
        const int rq = q - gq * F2B;       // float2 index within chunk (0..175)
        srcoff[i] = gq * ROWF2 + rq;       // float2 offset from block's x base
        maxoff[i] = gq * ROWF2 + (ROWF2 - 1); // clamp: stay within this row
        dstoff[i] = gq * F2BP + rq;        // padded LDS offset
    }
    const float2* __restrict__ xblk =
        reinterpret_cast<const float2*>(x) + (size_t)blockIdx.x * 4 * ROWF2;

    // ---- prologue: chunk 0 -> regs -> buf0 ; issue chunk 1 loads ----
    float2 stg[F2S];
    #pragma unroll
    for (int i = 0; i < F2S; ++i) stg[i] = xblk[srcoff[i]];
    #pragma unroll
    for (int i = 0; i < F2S; ++i) lbuf[dstoff[i]] = stg[i];
    #pragma unroll
    for (int i = 0; i < F2S; ++i) {
        const int idx = srcoff[i] + F2B;
        const int mx  = maxoff[i];
        stg[i] = xblk[idx < mx ? idx : mx];
    }

    // ---- recurrent state (replicated across the 16-lane group) ----
    float h1[Hn], h2[Hn];
    #pragma unroll
    for (int k = 0; k < Hn; ++k) { h1[k] = 0.f; h2[k] = 0.f; }

    // one time step; reads x[b,t,:] from lbuf at float2 offset `rb + s*11`
    auto step = [&](int rb, int s) {
        const float2* __restrict__ xr = &lbuf[rb + s * F2S];
        float2 xv[F2S];
        #pragma unroll
        for (int p = 0; p < F2S; ++p) xv[p] = xr[p];

        // layer 1: acc = b1 + x.w_ih0[j,:] + h1.w_hh0[j,:]
        float acc[4] = {bias1, 0.f, 0.f, 0.f};
        #pragma unroll
        for (int f = 0; f < Fn; ++f) {
            const float xf = (f & 1) ? xv[f >> 1].y : xv[f >> 1].x;
            acc[f & 3] = fmaf(xf, wih0[f], acc[f & 3]);
        }
        #pragma unroll
        for (int k = 0; k < Hn; ++k)
            acc[k & 3] = fmaf(h1[k], whh0[k], acc[k & 3]);
        const float h1n = fmaxf((acc[0] + acc[1]) + (acc[2] + acc[3]), 0.f);

        // broadcast new h1 across the 16-lane group
        #pragma unroll
        for (int k = 0; k < Hn; ++k)
            h1[k] = __int_as_float(__builtin_amdgcn_ds_bpermute(
                        permbase + (k << 2), __float_as_int(h1n)));

        // layer 2: bcc = b2 + h1_new.w_ih1[j,:] + h2.w_hh1[j,:]
        float bcc[4] = {bias2, 0.f, 0.f, 0.f};
        #pragma unroll
        for (int k = 0; k < Hn; ++k)
            bcc[k & 3] = fmaf(h1[k], wih1[k], bcc[k & 3]);
        #pragma unroll
        for (int k = 0; k < Hn; ++k)
            bcc[(k + 2) & 3] = fmaf(h2[k], whh1[k], bcc[(k + 2) & 3]);
        const float h2n = fmaxf((bcc[0] + bcc[1]) + (bcc[2] + bcc[3]), 0.f);

        #pragma unroll
        for (int k = 0; k < Hn; ++k)
            h2[k] = __int_as_float(__builtin_amdgcn_ds_bpermute(
                        permbase + (k << 2), __float_as_int(h2n)));
    };

    // ---- main loop: 62 full chunks, double-buffered, barrier-free ----
    for (int c = 0; c < NFULL; ++c) {
        const int rb = (c & 1) * BUF + g * F2BP;
        #pragma unroll 2
        for (int s = 0; s < CHUNK; ++s) step(rb, s);

        // stage chunk c+1 into the other buffer (waits vmcnt automatically)
        const int wb = ((c + 1) & 1) * BUF;
        #pragma unroll
        for (int i = 0; i < F2S; ++i) lbuf[wb + dstoff[i]] = stg[i];

        // issue loads for chunk c+2 (stay in flight across the next 16 steps)
        if (c <= NFULL - 2) {
            const int fb = F2B * (c + 2);
            #pragma unroll
            for (int i = 0; i < F2S; ++i) {
                const int idx = srcoff[i] + fb;
                const int mx  = maxoff[i];
                stg[i] = xblk[idx < mx ? idx : mx];
            }
        }
    }

    // ---- tail: 8 steps from buf0 (chunk 62 parity: 62 & 1 == 0) ----
    {
        const int rb = 0 * BUF + g * F2BP;
        #pragma unroll 2
        for (int s = 0; s < TAIL; ++s) step(rb, s);
    }

    // ---- head: out[b,:] = relu(h2) @ w_lin.T + b_lin ----
    if (j < Cn) {
        float o = blin;
        #pragma unroll
        for (int k = 0; k < Hn; ++k)
            o = fmaf(fmaxf(h2[k], 0.f), wlin[k], o);
        out[b * Cn + j] = o;
    }
}

} // namespace

extern "C" void kernel_launch(void* const* d_in, const int* in_sizes, int n_in,
                              void* d_out, int out_size, void* d_ws, size_t ws_size,
                              hipStream_t stream) {
    const float* x     = (const float*)d_in[0];
    const float* w_ih0 = (const float*)d_in[1];
    const float* w_hh0 = (const float*)d_in[2];
    const float* b_ih0 = (const float*)d_in[3];
    const float* b_hh0 = (const float*)d_in[4];
    const float* w_ih1 = (const float*)d_in[5];
    const float* w_hh1 = (const float*)d_in[6];
    const float* b_ih1 = (const float*)d_in[7];
    const float* b_hh1 = (const float*)d_in[8];
    const float* w_lin = (const float*)d_in[9];
    const float* b_lin = (const float*)d_in[10];
    float* out = (float*)d_out;

    // 1024 batch elements, 16 lanes each -> 256 blocks x 64 threads (1 wave/block)
    rnn_fused<<<dim3(256), dim3(64), 0, stream>>>(
        x, w_ih0, w_hh0, b_ih0, b_hh0,
        w_ih1, w_hh1, b_ih1, b_hh1, w_lin, b_lin, out);
}

// Round 2
// 177.362 us; speedup vs baseline: 1.4370x; 1.4370x over previous
//
#include <hip/hip_runtime.h>

typedef float v2f __attribute__((ext_vector_type(2)));

namespace {

constexpr int Tn = 1000;   // time steps
constexpr int Fn = 22;     // input features
constexpr int Hn = 10;     // hidden
constexpr int Cn = 4;      // classes

constexpr int UN   = 6;    // unroll (multiple of 3 so %3 set indices fold)
constexpr int MAIN = 166;  // 996 steps in main loop
constexpr int TAIL = 4;    // steps 996..999

__device__ __forceinline__ v2f fma2(v2f a, v2f b, v2f c) {
    return __builtin_elementwise_fma(a, b, c);
}
__device__ __forceinline__ v2f mk2(float a, float b) { v2f r; r.x = a; r.y = b; return r; }
__device__ __forceinline__ float bperm(int addr, float v) {
    return __int_as_float(__builtin_amdgcn_ds_bpermute(addr, __float_as_int(v)));
}

__global__ __launch_bounds__(64, 1) void rnn_fused(
    const float* __restrict__ x,
    const float* __restrict__ w_ih0, const float* __restrict__ w_hh0,
    const float* __restrict__ b_ih0, const float* __restrict__ b_hh0,
    const float* __restrict__ w_ih1, const float* __restrict__ w_hh1,
    const float* __restrict__ b_ih1, const float* __restrict__ b_hh1,
    const float* __restrict__ w_lin, const float* __restrict__ b_lin,
    float* __restrict__ out)
{
    const int lane = threadIdx.x;          // one wave per block
    const int g    = lane >> 4;            // 16-lane group -> one batch
    const int j    = lane & 15;            // neuron id within group
    const int b    = blockIdx.x * 4 + g;
    const int jr   = (j < Hn) ? j : 0;
    const int jc   = (j < Cn) ? j : 0;
    const int pb   = (lane & 48) << 2;     // byte addr of group's lane 0

    // bpermute byte addresses for neurons 0..9 of this group
    int bpa[Hn];
    #pragma unroll
    for (int k = 0; k < Hn; ++k) bpa[k] = pb + (k << 2);

    // ---- packed per-neuron weights ----
    v2f wih0p[11], whh0p[5], wih1p[5], whh1p[5], wlinp[5];
    #pragma unroll
    for (int p = 0; p < 11; ++p)
        wih0p[p] = mk2(w_ih0[jr * Fn + 2 * p], w_ih0[jr * Fn + 2 * p + 1]);
    #pragma unroll
    for (int p = 0; p < 5; ++p) {
        whh0p[p] = mk2(w_hh0[jr * Hn + 2 * p], w_hh0[jr * Hn + 2 * p + 1]);
        wih1p[p] = mk2(w_ih1[jr * Hn + 2 * p], w_ih1[jr * Hn + 2 * p + 1]);
        whh1p[p] = mk2(w_hh1[jr * Hn + 2 * p], w_hh1[jr * Hn + 2 * p + 1]);
        wlinp[p] = mk2(w_lin[jc * Hn + 2 * p], w_lin[jc * Hn + 2 * p + 1]);
    }
    const v2f bz  = mk2(b_ih0[jr] + b_hh0[jr], 0.f);
    const v2f bd  = mk2(b_ih1[jr] + b_hh1[jr], 0.f);
    const float blv = b_lin[jc];

    const float* xrow = x + (size_t)b * (Tn * Fn);

    // ---- x register sets: xv[set*11 + p], set = t % 3 ----
    v2f xv[33];
    #pragma unroll
    for (int k = 0; k < 3; ++k)
        #pragma unroll
        for (int p = 0; p < 11; ++p)
            xv[k * 11 + p] = *(const v2f*)(xrow + k * Fn + 2 * p);

    // recurrent state, replicated across the 16-lane group (pk pairs)
    v2f h1p[5], h2p[5];
    #pragma unroll
    for (int k = 0; k < 5; ++k) { h1p[k] = mk2(0.f, 0.f); h2p[k] = mk2(0.f, 0.f); }

    // carried z accumulators (bias1 + x[t] . w_ih0, unreduced pk pairs)
    v2f zA, zB;
    auto zcomp = [&](int zi) {
        zA = fma2(xv[zi + 0], wih0p[0], bz);
        zB = xv[zi + 1] * wih0p[1];
        zA = fma2(xv[zi + 2],  wih0p[2],  zA);
        zB = fma2(xv[zi + 3],  wih0p[3],  zB);
        zA = fma2(xv[zi + 4],  wih0p[4],  zA);
        zB = fma2(xv[zi + 5],  wih0p[5],  zB);
        zA = fma2(xv[zi + 6],  wih0p[6],  zA);
        zB = fma2(xv[zi + 7],  wih0p[7],  zB);
        zA = fma2(xv[zi + 8],  wih0p[8],  zA);
        zB = fma2(xv[zi + 9],  wih0p[9],  zB);
        zA = fma2(xv[zi + 10], wih0p[10], zA);
    };
    zcomp(0);  // z for t = 0

    // one pipelined time step.
    //   znext: xv base index for z[t+1] (t+1 mod 3)*11 ; do_z: compute it
    //   ldst : xv base index to receive x[t+3] (-1 = skip) ; lsrc: its address
    auto step = [&](int znext, bool do_z, int ldst, const float* lsrc) {
        // L1 finish: s1 = z[t] + h1 . w_hh0 ; h1n = relu(s1)
        v2f aA = fma2(h1p[0], whh0p[0], zA);
        v2f aB = fma2(h1p[1], whh0p[1], zB);
        aA = fma2(h1p[2], whh0p[2], aA);
        aB = fma2(h1p[3], whh0p[3], aB);
        aA = fma2(h1p[4], whh0p[4], aA);
        v2f ap = aA + aB;
        const float h1n = fmaxf(ap.x + ap.y, 0.f);

        // broadcast h1n across the group (in flight during z'/Dpre/loads)
        const float n0 = bperm(bpa[0], h1n), n1 = bperm(bpa[1], h1n);
        const float n2 = bperm(bpa[2], h1n), n3 = bperm(bpa[3], h1n);
        const float n4 = bperm(bpa[4], h1n), n5 = bperm(bpa[5], h1n);
        const float n6 = bperm(bpa[6], h1n), n7 = bperm(bpa[7], h1n);
        const float n8 = bperm(bpa[8], h1n), n9 = bperm(bpa[9], h1n);

        // Dpre: bias2 + h2[t-1] . w_hh1  (independent of bp1)
        v2f dA = fma2(h2p[0], whh1p[0], bd);
        v2f dB = h2p[1] * whh1p[1];
        dA = fma2(h2p[2], whh1p[2], dA);
        dB = fma2(h2p[3], whh1p[3], dB);
        dA = fma2(h2p[4], whh1p[4], dA);

        // z for t+1 (independent of bp1)
        if (do_z) zcomp(znext);

        // issue x loads for t+3 (VMEM pipe, independent)
        if (ldst >= 0) {
            #pragma unroll
            for (int p = 0; p < 11; ++p)
                xv[ldst + p] = *(const v2f*)(lsrc + 2 * p);
        }

        // commit broadcast h1
        h1p[0] = mk2(n0, n1); h1p[1] = mk2(n2, n3); h1p[2] = mk2(n4, n5);
        h1p[3] = mk2(n6, n7); h1p[4] = mk2(n8, n9);

        // Dpost: += h1[t] . w_ih1 ; h2n = relu
        dA = fma2(h1p[0], wih1p[0], dA);
        dB = fma2(h1p[1], wih1p[1], dB);
        dA = fma2(h1p[2], wih1p[2], dA);
        dB = fma2(h1p[3], wih1p[3], dB);
        dA = fma2(h1p[4], wih1p[4], dA);
        v2f dp = dA + dB;
        const float h2n = fmaxf(dp.x + dp.y, 0.f);

        // broadcast h2n (RT hidden under next step's L1/bp1/z')
        h2p[0] = mk2(bperm(bpa[0], h2n), bperm(bpa[1], h2n));
        h2p[1] = mk2(bperm(bpa[2], h2n), bperm(bpa[3], h2n));
        h2p[2] = mk2(bperm(bpa[4], h2n), bperm(bpa[5], h2n));
        h2p[3] = mk2(bperm(bpa[6], h2n), bperm(bpa[7], h2n));
        h2p[4] = mk2(bperm(bpa[8], h2n), bperm(bpa[9], h2n));
    };

    // ---- main loop: t = 6c + s, s = 0..5 ; all prefetches in-bounds ----
    for (int c = 0; c < MAIN; ++c) {
        #pragma unroll
        for (int s = 0; s < UN; ++s) {
            step(((s + 1) % 3) * 11, true, (s % 3) * 11, xrow + (s + 3) * Fn);
        }
        xrow += UN * Fn;
    }

    // ---- tail: t = 996..999 ; prefetch only t+3 == 999, no z[1000] ----
    #pragma unroll
    for (int s = 0; s < TAIL; ++s) {
        step(((s + 1) % 3) * 11, s < 3, (s == 0) ? 0 : -1, xrow + 3 * Fn);
    }

    // ---- head: out[b,:] = relu(h2[999]) @ w_lin.T + b_lin (h2 already >= 0) ----
    if (j < Cn) {
        v2f oA = fma2(h2p[0], wlinp[0], mk2(blv, 0.f));
        v2f oB = h2p[1] * wlinp[1];
        oA = fma2(h2p[2], wlinp[2], oA);
        oB = fma2(h2p[3], wlinp[3], oB);
        oA = fma2(h2p[4], wlinp[4], oA);
        v2f op = oA + oB;
        out[b * Cn + j] = op.x + op.y;
    }
}

} // namespace

extern "C" void kernel_launch(void* const* d_in, const int* in_sizes, int n_in,
                              void* d_out, int out_size, void* d_ws, size_t ws_size,
                              hipStream_t stream) {
    const float* x     = (const float*)d_in[0];
    const float* w_ih0 = (const float*)d_in[1];
    const float* w_hh0 = (const float*)d_in[2];
    const float* b_ih0 = (const float*)d_in[3];
    const float* b_hh0 = (const float*)d_in[4];
    const float* w_ih1 = (const float*)d_in[5];
    const float* w_hh1 = (const float*)d_in[6];
    const float* b_ih1 = (const float*)d_in[7];
    const float* b_hh1 = (const float*)d_in[8];
    const float* w_lin = (const float*)d_in[9];
    const float* b_lin = (const float*)d_in[10];
    float* out = (float*)d_out;

    rnn_fused<<<dim3(256), dim3(64), 0, stream>>>(
        x, w_ih0, w_hh0, b_ih0, b_hh0,
        w_ih1, w_hh1, b_ih1, b_hh1, w_lin, b_lin, out);
}